// Round 2
// baseline (22.717 us; speedup 1.0000x reference)
//
#include <hip/hip_runtime.h>

// PrRoIPool forward. features [2,64,100,100] f32, rois [256,5], out [256,64,7,7].
//
// Separable analytic integral of bilinear interp over each bin:
//   out[n,c,p,q] = (1/area) * sum_h sum_w f[b,c,h,w] * Wy[n,p,h] * Wx[n,q,w]
// Hat-kernel support per axis is bw+2 < 7.72 px -> 8 pixels max.
//
// Round-2 structure:
//  - each thread computes 4 outputs (same n,p,q; channels c0, c0+16, c0+32,
//    c0+48) so the per-(n,p,q) weight computation is amortized 4x
//  - x-window widened to 12 px, start aligned down to a multiple of 4
//    (clamped to FW-12) -> row loads are three 16B-aligned float4s;
//    out-of-support pixels get exactly-zero weights, so this is exact
//  - branchless hat-cdf: cdf(t) = 0.5 + s*(1-|s|/2), s=clamp(t,-1,1);
//    the 0.5 cancels in the difference.

constexpr int OUT_H = 7, OUT_W = 7;
constexpr float SPATIAL_SCALE = 0.25f;
constexpr int CH = 64, FH = 100, FW = 100;
constexpr int SUP_Y = 8;    // y support window
constexpr int SUP_X = 12;   // aligned x window (covers 8-px support, 4-aligned)
constexpr int CPT = 4;      // channels per thread

__device__ __forceinline__ float hat_cdf_c(float t) {
    // cdf(t) minus the constant 0.5 (constant cancels in differences):
    // s = clamp(t,-1,1); return s*(1 - 0.5*|s|)
    float s = fminf(fmaxf(t, -1.0f), 1.0f);
    return s * fmaf(-0.5f, fabsf(s), 1.0f);
}

__global__ __launch_bounds__(256) void prroi_pool_kernel(
    const float* __restrict__ feat, const float* __restrict__ rois,
    float* __restrict__ out, int n_rois) {
    int idx = blockIdx.x * 256 + threadIdx.x;
    int total = n_rois * (CH / CPT) * OUT_H * OUT_W;
    if (idx >= total) return;

    // idx = ((n*16 + c0)*49 + p*7 + q), pq fastest so a wave shares one plane
    int pq = idx % (OUT_H * OUT_W);
    int t = idx / (OUT_H * OUT_W);
    int c0 = t & (CH / CPT - 1);
    int n = t >> 4;
    int q = pq % OUT_W;
    int p = pq / OUT_W;

    const float* r = rois + n * 5;
    int b = (int)r[0];
    float x1 = r[1] * SPATIAL_SCALE;
    float y1 = r[2] * SPATIAL_SCALE;
    float x2 = r[3] * SPATIAL_SCALE;
    float y2 = r[4] * SPATIAL_SCALE;
    float bw = fmaxf(x2 - x1, 0.0f) * (1.0f / OUT_W);
    float bh = fmaxf(y2 - y1, 0.0f) * (1.0f / OUT_H);

    float u0x = x1 + (float)q * bw, u1x = u0x + bw;
    float u0y = y1 + (float)p * bh, u1y = u0y + bh;

    // y window: 8 px, start clamped into image
    int hs = min(max((int)ceilf(u0y - 1.0f), 0), FH - SUP_Y);
    // x window: 12 px, start = 4-aligned floor of the 8-px window start
    int ws8 = min(max((int)ceilf(u0x - 1.0f), 0), FW - 8);
    int wsa = min(ws8 & ~3, FW - SUP_X);

    float wx[SUP_X], wy[SUP_Y];
#pragma unroll
    for (int j = 0; j < SUP_X; ++j) {
        float px = (float)(wsa + j);
        wx[j] = hat_cdf_c(u1x - px) - hat_cdf_c(u0x - px);
    }
#pragma unroll
    for (int i = 0; i < SUP_Y; ++i) {
        float py = (float)(hs + i);
        wy[i] = hat_cdf_c(u1y - py) - hat_cdf_c(u0y - py);
    }

    float area = bw * bh;
    float inv_area = 1.0f / fmaxf(area, 1e-12f);
    bool ok = area > 0.0f;

    // 4 channel planes: c = c0 + 16k
#pragma unroll
    for (int k = 0; k < CPT; ++k) {
        int c = c0 + k * (CH / CPT);
        const float* fb = feat + (((size_t)b * CH + c) * FH + hs) * FW + wsa;
        float acc = 0.0f;
#pragma unroll
        for (int i = 0; i < SUP_Y; ++i) {
            const float4* row = reinterpret_cast<const float4*>(fb + i * FW);
            float4 v0 = row[0], v1 = row[1], v2 = row[2];
            float rs = 0.0f;
            rs = fmaf(wx[0], v0.x, rs);
            rs = fmaf(wx[1], v0.y, rs);
            rs = fmaf(wx[2], v0.z, rs);
            rs = fmaf(wx[3], v0.w, rs);
            rs = fmaf(wx[4], v1.x, rs);
            rs = fmaf(wx[5], v1.y, rs);
            rs = fmaf(wx[6], v1.z, rs);
            rs = fmaf(wx[7], v1.w, rs);
            rs = fmaf(wx[8], v2.x, rs);
            rs = fmaf(wx[9], v2.y, rs);
            rs = fmaf(wx[10], v2.z, rs);
            rs = fmaf(wx[11], v2.w, rs);
            acc = fmaf(wy[i], rs, acc);
        }
        out[(size_t)n * (CH * OUT_H * OUT_W) + c * (OUT_H * OUT_W) + pq] =
            ok ? acc * inv_area : 0.0f;
    }
}

extern "C" void kernel_launch(void* const* d_in, const int* in_sizes, int n_in,
                              void* d_out, int out_size, void* d_ws, size_t ws_size,
                              hipStream_t stream) {
    const float* feat = (const float*)d_in[0];
    const float* rois = (const float*)d_in[1];
    float* out = (float*)d_out;
    int n_rois = in_sizes[1] / 5;
    int total = n_rois * (CH / CPT) * OUT_H * OUT_W;
    int blocks = (total + 255) / 256;
    hipLaunchKernelGGL(prroi_pool_kernel, dim3(blocks), dim3(256), 0, stream,
                       feat, rois, out, n_rois);
}

// Round 3
// 15.627 us; speedup vs baseline: 1.4538x; 1.4538x over previous
//
#include <hip/hip_runtime.h>

// PrRoIPool forward. features [2,64,100,100] f32, rois [256,5], out [256,64,7,7].
//
// Separable analytic integral of bilinear interp over each bin:
//   out[n,c,p,q] = (1/area) * sum_h sum_w f[b,c,h,w] * Wy[n,p,h] * Wx[n,q,w]
// Hat support per axis is bw+2 < 7.72 px -> fixed 8-px window, start clamped
// to [0, dim-8]; pixels outside the support get exactly-zero weights.
//
// Round-3 (post-mortem of r2): keep round-1's 1-thread/output mapping (max
// wave count = best measured latency hiding); cut per-WAVE instruction count:
//  - branchless hat-cdf via med3 + free |.| modifier (cdf(t)-0.5 = s*(1-|s|/2))
//  - incremental weight arguments (no int->float cvt per tap)
//  - two unaligned dwordx4 loads per row (gfx950 allows 4B-aligned x4)
//  - two independent accumulator chains for ILP

constexpr int OUT_H = 7, OUT_W = 7;
constexpr float SPATIAL_SCALE = 0.25f;
constexpr int CH = 64, FH = 100, FW = 100;
constexpr int SUP = 8;

typedef float f4u __attribute__((ext_vector_type(4), aligned(4)));

__device__ __forceinline__ float hat_cdf_c(float t) {
    // cdf(t) - 0.5 (constant cancels in differences): s=clamp(t,-1,1),
    // s*(1-|s|/2).  min(max()) -> v_med3_f32; |s| is a free input modifier.
    float s = fminf(fmaxf(t, -1.0f), 1.0f);
    return s * fmaf(-0.5f, fabsf(s), 1.0f);
}

__global__ __launch_bounds__(256) void prroi_pool_kernel(
    const float* __restrict__ feat, const float* __restrict__ rois,
    float* __restrict__ out, int n_rois) {
    int idx = blockIdx.x * 256 + threadIdx.x;
    int total = n_rois * CH * OUT_H * OUT_W;
    if (idx >= total) return;

    int pq = idx % (OUT_H * OUT_W);
    int t = idx / (OUT_H * OUT_W);
    int c = t & (CH - 1);
    int n = t >> 6;
    int q = pq % OUT_W;
    int p = pq / OUT_W;

    const float* r = rois + n * 5;
    int b = (int)r[0];
    float x1 = r[1] * SPATIAL_SCALE;
    float y1 = r[2] * SPATIAL_SCALE;
    float x2 = r[3] * SPATIAL_SCALE;
    float y2 = r[4] * SPATIAL_SCALE;
    float bw = fmaxf(x2 - x1, 0.0f) * (1.0f / OUT_W);
    float bh = fmaxf(y2 - y1, 0.0f) * (1.0f / OUT_H);

    float u0x = x1 + (float)q * bw, u1x = u0x + bw;
    float u0y = y1 + (float)p * bh, u1y = u0y + bh;

    int ws = min(max((int)ceilf(u0x - 1.0f), 0), FW - SUP);
    int hs = min(max((int)ceilf(u0y - 1.0f), 0), FH - SUP);

    float wx[SUP], wy[SUP];
    float dx0 = u0x - (float)ws, dx1 = u1x - (float)ws;
    float dy0 = u0y - (float)hs, dy1 = u1y - (float)hs;
#pragma unroll
    for (int j = 0; j < SUP; ++j) {
        wx[j] = hat_cdf_c(dx1) - hat_cdf_c(dx0);
        wy[j] = hat_cdf_c(dy1) - hat_cdf_c(dy0);
        dx0 -= 1.0f; dx1 -= 1.0f;
        dy0 -= 1.0f; dy1 -= 1.0f;
    }

    const float* fb = feat + (((size_t)b * CH + c) * FH + hs) * FW + ws;
    float acc0 = 0.0f, acc1 = 0.0f;
#pragma unroll
    for (int i = 0; i < SUP; ++i) {
        const f4u* row = reinterpret_cast<const f4u*>(fb + i * FW);
        f4u v0 = row[0], v1 = row[1];
        float rsA = fmaf(wx[0], v0.x,
                    fmaf(wx[1], v0.y,
                    fmaf(wx[2], v0.z, wx[3] * v0.w)));
        float rsB = fmaf(wx[4], v1.x,
                    fmaf(wx[5], v1.y,
                    fmaf(wx[6], v1.z, wx[7] * v1.w)));
        acc0 = fmaf(wy[i], rsA, acc0);
        acc1 = fmaf(wy[i], rsB, acc1);
    }
    float acc = acc0 + acc1;

    float area = bw * bh;
    out[idx] = (area > 0.0f) ? acc / fmaxf(area, 1e-12f) : 0.0f;
}

extern "C" void kernel_launch(void* const* d_in, const int* in_sizes, int n_in,
                              void* d_out, int out_size, void* d_ws, size_t ws_size,
                              hipStream_t stream) {
    const float* feat = (const float*)d_in[0];
    const float* rois = (const float*)d_in[1];
    float* out = (float*)d_out;
    int n_rois = in_sizes[1] / 5;
    int total = n_rois * CH * OUT_H * OUT_W;
    int blocks = (total + 255) / 256;
    hipLaunchKernelGGL(prroi_pool_kernel, dim3(blocks), dim3(256), 0, stream,
                       feat, rois, out, n_rois);
}

// Round 4
// 15.089 us; speedup vs baseline: 1.5056x; 1.0356x over previous
//
#include <hip/hip_runtime.h>

// PrRoIPool forward. features [2,64,100,100] f32, rois [256,5], out [256,64,7,7].
//
// Separable analytic integral of bilinear interp over each bin; fixed 8-px
// per-axis windows (support bw+2 < 7.72 px), window start clamped in-image,
// out-of-support pixels get exactly-zero weights.
//
// Round-4: r1/r3 both 15.6us despite 4x VMEM & 2x VALU instruction deltas ->
// bound is cache-locality-invariant. Theory: ~150 MB of per-(n,c) patch
// re-reads thrash the 4 MiB per-XCD L2 (working set = all 5.12 MB of
// features), so traffic is served at L3 rate (~150MB/15.6us ~= 9.6 TB/s).
// Fix: channel-major work decode + bijective XCD block swizzle (3136 = 8*392)
// so XCD k only touches channels [8k, 8k+8) x 2 batches = 640 KB -> L2-hits.
// Kernel body identical to r3 to isolate the locality lever.

constexpr int OUT_H = 7, OUT_W = 7;
constexpr float SPATIAL_SCALE = 0.25f;
constexpr int CH = 64, FH = 100, FW = 100;
constexpr int SUP = 8;
constexpr int N_XCD = 8;

typedef float f4u __attribute__((ext_vector_type(4), aligned(4)));

__device__ __forceinline__ float hat_cdf_c(float t) {
    // cdf(t) - 0.5 (constant cancels in differences): s=clamp(t,-1,1),
    // s*(1-|s|/2).  min(max()) -> v_med3_f32; |s| is a free input modifier.
    float s = fminf(fmaxf(t, -1.0f), 1.0f);
    return s * fmaf(-0.5f, fabsf(s), 1.0f);
}

__global__ __launch_bounds__(256) void prroi_pool_kernel(
    const float* __restrict__ feat, const float* __restrict__ rois,
    float* __restrict__ out, int n_rois) {
    // Bijective XCD swizzle: hardware round-robins blocks over 8 XCDs, so
    // give block b the data chunk (b%8)*cpx + b/8 -> XCD k gets a contiguous
    // chunk of the c-major work range. nwg = 3136 = 8*392 exactly.
    int nwg = gridDim.x;
    int cpx = nwg / N_XCD;  // 392
    int chunk = (blockIdx.x % N_XCD) * cpx + blockIdx.x / N_XCD;
    int t = chunk * 256 + threadIdx.x;
    int total = n_rois * CH * OUT_H * OUT_W;
    if (t >= total) return;

    // c-major decode: for fixed c there are n_rois*49 = 12544 work items.
    int per_c = n_rois * (OUT_H * OUT_W);
    int c = t / per_c;
    int rem = t - c * per_c;
    int n = rem / (OUT_H * OUT_W);
    int pq = rem - n * (OUT_H * OUT_W);
    int q = pq % OUT_W;
    int p = pq / OUT_W;

    const float* r = rois + n * 5;
    int b = (int)r[0];
    float x1 = r[1] * SPATIAL_SCALE;
    float y1 = r[2] * SPATIAL_SCALE;
    float x2 = r[3] * SPATIAL_SCALE;
    float y2 = r[4] * SPATIAL_SCALE;
    float bw = fmaxf(x2 - x1, 0.0f) * (1.0f / OUT_W);
    float bh = fmaxf(y2 - y1, 0.0f) * (1.0f / OUT_H);

    float u0x = x1 + (float)q * bw, u1x = u0x + bw;
    float u0y = y1 + (float)p * bh, u1y = u0y + bh;

    int ws = min(max((int)ceilf(u0x - 1.0f), 0), FW - SUP);
    int hs = min(max((int)ceilf(u0y - 1.0f), 0), FH - SUP);

    float wx[SUP], wy[SUP];
    float dx0 = u0x - (float)ws, dx1 = u1x - (float)ws;
    float dy0 = u0y - (float)hs, dy1 = u1y - (float)hs;
#pragma unroll
    for (int j = 0; j < SUP; ++j) {
        wx[j] = hat_cdf_c(dx1) - hat_cdf_c(dx0);
        wy[j] = hat_cdf_c(dy1) - hat_cdf_c(dy0);
        dx0 -= 1.0f; dx1 -= 1.0f;
        dy0 -= 1.0f; dy1 -= 1.0f;
    }

    const float* fb = feat + (((size_t)b * CH + c) * FH + hs) * FW + ws;
    float acc0 = 0.0f, acc1 = 0.0f;
#pragma unroll
    for (int i = 0; i < SUP; ++i) {
        const f4u* row = reinterpret_cast<const f4u*>(fb + i * FW);
        f4u v0 = row[0], v1 = row[1];
        float rsA = fmaf(wx[0], v0.x,
                    fmaf(wx[1], v0.y,
                    fmaf(wx[2], v0.z, wx[3] * v0.w)));
        float rsB = fmaf(wx[4], v1.x,
                    fmaf(wx[5], v1.y,
                    fmaf(wx[6], v1.z, wx[7] * v1.w)));
        acc0 = fmaf(wy[i], rsA, acc0);
        acc1 = fmaf(wy[i], rsB, acc1);
    }
    float acc = acc0 + acc1;

    float area = bw * bh;
    float res = (area > 0.0f) ? acc / fmaxf(area, 1e-12f) : 0.0f;
    // out layout is n-major: out[((n*CH + c)*49) + pq]
    out[((size_t)n * CH + c) * (OUT_H * OUT_W) + pq] = res;
}

extern "C" void kernel_launch(void* const* d_in, const int* in_sizes, int n_in,
                              void* d_out, int out_size, void* d_ws, size_t ws_size,
                              hipStream_t stream) {
    const float* feat = (const float*)d_in[0];
    const float* rois = (const float*)d_in[1];
    float* out = (float*)d_out;
    int n_rois = in_sizes[1] / 5;
    int total = n_rois * CH * OUT_H * OUT_W;
    int blocks = (total + 255) / 256;  // 3136 = 8 * 392
    hipLaunchKernelGGL(prroi_pool_kernel, dim3(blocks), dim3(256), 0, stream,
                       feat, rois, out, n_rois);
}